// Round 7
// baseline (5283.049 us; speedup 1.0000x reference)
//
#include <hip/hip_runtime.h>
#include <hip/hip_fp16.h>

// Problem constants
#define TT 2048
#define II 1739
#define HN 256
#define H3 768
#define L2E 1.44269504088896f

typedef _Float16 h2 __attribute__((ext_vector_type(2)));

__device__ __forceinline__ float fdot2(h2 a, h2 b, float c) {
#if defined(__has_builtin)
#if __has_builtin(__builtin_amdgcn_fdot2)
  return __builtin_amdgcn_fdot2(a, b, c, false);
#else
  return fmaf((float)a[0], (float)b[0], fmaf((float)a[1], (float)b[1], c));
#endif
#else
  return fmaf((float)a[0], (float)b[0], fmaf((float)a[1], (float)b[1], c));
#endif
}

__device__ __forceinline__ float fast_exp2(float x) {
#if defined(__has_builtin)
#if __has_builtin(__builtin_amdgcn_exp2f)
  return __builtin_amdgcn_exp2f(x);
#else
  return exp2f(x);
#endif
#else
  return exp2f(x);
#endif
}

__device__ __forceinline__ float fast_rcp(float x) {
#if defined(__has_builtin)
#if __has_builtin(__builtin_amdgcn_rcpf)
  return __builtin_amdgcn_rcpf(x);
#else
  return 1.f / x;
#endif
#else
  return 1.f / x;
#endif
}

template <int CTRL>
__device__ __forceinline__ float dpp_qperm(float v) {
  int r = __builtin_amdgcn_update_dpp(0, __builtin_bit_cast(int, v), CTRL, 0xF, 0xF, true);
  return __builtin_bit_cast(float, r);
}

// C[M,N] = ((A[M,K] @ B[N,K]^T) + bias1[n] + (n < b2lim ? bias2[n] : 0)) * (n < slim ? s_lo : s_hi)
// 64x64 tile, 256 threads, 4x4 micro-tile per thread.
__global__ __launch_bounds__(256) void gemm_abt(
    const float* __restrict__ A, int M, int K,
    const float* __restrict__ B, int N,
    const float* __restrict__ bias1, const float* __restrict__ bias2, int b2lim,
    float s_lo, float s_hi, int slim,
    float* __restrict__ C) {
  __shared__ float As[16][64];
  __shared__ float Bs[16][64];
  const int tid = threadIdx.x;
  const int m0 = blockIdx.y * 64, n0 = blockIdx.x * 64;
  const int lr = tid >> 2;        // 0..63  (row within tile for loads)
  const int lk = (tid & 3) * 4;   // 0,4,8,12
  const int cx = tid & 15, cy = tid >> 4;
  float acc[4][4] = {};

  for (int k0 = 0; k0 < K; k0 += 16) {
#pragma unroll
    for (int i = 0; i < 4; ++i) {
      int k = k0 + lk + i;
      As[lk + i][lr] = (k < K) ? A[(size_t)(m0 + lr) * K + k] : 0.f;
      int bn = n0 + lr;
      Bs[lk + i][lr] = (k < K && bn < N) ? B[(size_t)bn * K + k] : 0.f;
    }
    __syncthreads();
#pragma unroll
    for (int k = 0; k < 16; ++k) {
      float4 av = *(const float4*)&As[k][cy * 4];
      float4 bv = *(const float4*)&Bs[k][cx * 4];
      const float aa[4] = {av.x, av.y, av.z, av.w};
      const float bb[4] = {bv.x, bv.y, bv.z, bv.w};
#pragma unroll
      for (int i = 0; i < 4; ++i)
#pragma unroll
        for (int j = 0; j < 4; ++j) acc[i][j] = fmaf(aa[i], bb[j], acc[i][j]);
    }
    __syncthreads();
  }
#pragma unroll
  for (int i = 0; i < 4; ++i) {
    int m = m0 + cy * 4 + i;
#pragma unroll
    for (int j = 0; j < 4; ++j) {
      int n = n0 + cx * 4 + j;
      if (n < N) {
        float b = bias1 ? bias1[n] : 0.f;
        if (bias2 && n < b2lim) b += bias2[n];
        float s = (n < slim) ? s_lo : s_hi;
        C[(size_t)m * N + n] = (acc[i][j] + b) * s;
      }
    }
  }
}

// Sequential GRU scan on a single CU (1 block, 512 threads = 8 waves).
// Structure = round 4 (best measured: 2140 us/scan, no spill) with three
// latency fixes:
//
//  1. RAW BARRIER: __syncthreads() compiles to s_waitcnt vmcnt(0)
//     lgkmcnt(0) + s_barrier -> every step drained the hs_out GLOBAL
//     store (~200-400 cy to L2) before any wave proceeded. Nothing needs
//     that: hs_out is read only after kernel end; x-loads are register-
//     tracked. Only the LDS h-write needs ordering. So: explicit
//     s_waitcnt lgkmcnt(0) + raw s_barrier, fenced with sched_barrier(0)
//     (rule #18) -> global stores fire-and-forget, vmcnt never drains.
//  2. SPLIT CHAINS: each gate's 32 fdot2 were one serial dependence
//     chain (~128+ cy); now 2 accumulators x 16 -> chain halved.
//  3. X-PREFETCH: step t issues t+1's x loads; a full matvec of slack
//     before use. Over-read at t=2047 lands in the adjacent workspace
//     buffer (allocated, unused).
//
// Thread layout (= r4): quad q (= wv*16 + lane>>2, q in [0,128)) owns
// hidden units {2q, 2q+1}; lane kc = lane&3 covers k-chunk [64kc, +64).
// wreg[uu*3+gg][.] = gate row (u0+uu) + gg*256, pre-scaled for exp2 gates.
// After the quad DPP butterfly all 4 lanes hold hr/hz/hn for both units
// -> gates fully local, ONE barrier per step, double-buffered f16 h.
//
// hbuf layout (per buffer, 160 dwords): h (256 f16 = 128 dwords) in 4
// k-chunks of 32 dwords at stride 40 -> the 4 distinct per-quad b128
// read addresses hit disjoint bank groups (0 conflicts, verified r1-r6).
__global__ __launch_bounds__(512) void gru_seq(
    const float* __restrict__ xp,      // [T, 768], pre-scaled by L2E/2L2E
    const float* __restrict__ Whh,     // [768, 256]
    const float* __restrict__ bhh,     // [768]
    const float* __restrict__ h0,      // [256] or nullptr (zeros)
    float* __restrict__ hs_out,        // [T, 256] or nullptr
    float* __restrict__ hT_out) {      // [256] or nullptr
  __shared__ __align__(16) uint hbufd[2][160];

  const int tid = threadIdx.x;
  const int lane = tid & 63;
  const int wv = tid >> 6;              // 0..7
  const int kc = lane & 3;              // k-chunk [64*kc, 64*kc+64)
  const int q = wv * 16 + (lane >> 2);  // 0..127; units 2q, 2q+1
  const int u0 = 2 * q;

  // wreg[uu*3+gg]: unit u0+uu, gate gg (0=r,1=z,2=n), pre-scaled.
  h2 wreg[6][32];
#pragma unroll
  for (int uu = 0; uu < 2; ++uu) {
#pragma unroll
    for (int gg = 0; gg < 3; ++gg) {
      const float sc = (gg == 2) ? (2.f * L2E) : L2E;
      const float* wr = Whh + (size_t)(u0 + uu + gg * HN) * HN + kc * 64;
#pragma unroll
      for (int p = 0; p < 32; ++p) {
        float2 f = *(const float2*)(wr + 2 * p);
        wreg[uu * 3 + gg][p] = h2{(_Float16)(f.x * sc), (_Float16)(f.y * sc)};
      }
    }
  }

  float hj0 = h0 ? h0[u0] : 0.f;
  float hj1 = h0 ? h0[u0 + 1] : 0.f;
  const float bhn0 = bhh[2 * HN + u0] * (2.f * L2E);
  const float bhn1 = bhh[2 * HN + u0 + 1] * (2.f * L2E);

  if (tid < 128) {
    float a = h0 ? h0[2 * tid] : 0.f;
    float b = h0 ? h0[2 * tid + 1] : 0.f;
    h2 pv = h2{(_Float16)a, (_Float16)b};
    hbufd[0][(tid >> 5) * 40 + (tid & 31)] = __builtin_bit_cast(uint, pv);
  }
  __syncthreads();

  const int wadr = (q >> 5) * 40 + (q & 31);

  // x-prefetch registers: current step's values live here; next step's
  // loads are issued at the top of each iteration.
  const float* xq = xp + u0;
  float2 xr = *(const float2*)(xq);
  float2 xz = *(const float2*)(xq + HN);
  float2 xn = *(const float2*)(xq + 2 * HN);

  for (int t = 0; t < TT; ++t) {
    // Issue next step's x loads now (consumed next iteration).
    const float* xqn = xq + (size_t)(t + 1) * H3;
    float2 xr_n = *(const float2*)(xqn);
    float2 xz_n = *(const float2*)(xqn + HN);
    float2 xn_n = *(const float2*)(xqn + 2 * HN);

    // Matvec: 6 rows x 64 k per thread, 2 accumulators per row
    // (chain 16 deep instead of 32).
    const uint* hb = &hbufd[t & 1][kc * 40];
    float aA[6] = {0.f, 0.f, 0.f, 0.f, 0.f, 0.f};
    float aB[6] = {0.f, 0.f, 0.f, 0.f, 0.f, 0.f};
#pragma unroll
    for (int qq = 0; qq < 8; ++qq) {
      uint4 v = *(const uint4*)&hb[qq * 4];
      uint hwv[4] = {v.x, v.y, v.z, v.w};
      float* ac = (qq & 1) ? aB : aA;
#pragma unroll
      for (int i = 0; i < 6; ++i)
#pragma unroll
        for (int p = 0; p < 4; ++p)
          ac[i] = fdot2(wreg[i][qq * 4 + p], __builtin_bit_cast(h2, hwv[p]), ac[i]);
    }

    // Merge split accumulators + quad butterfly (all 4 lanes end with
    // the full, bit-identical k-sum).
    float a[6];
#pragma unroll
    for (int i = 0; i < 6; ++i) {
      float v = aA[i] + aB[i];
      v += dpp_qperm<0xB1>(v);  // xor 1
      v += dpp_qperm<0x4E>(v);  // xor 2
      a[i] = v;
    }

    // Gates, fully local (args pre-scaled by log2e / 2log2e).
    float r0 = fast_rcp(1.f + fast_exp2(-(xr.x + a[0])));
    float z0 = fast_rcp(1.f + fast_exp2(-(xz.x + a[1])));
    float n0 = fmaf(2.f, fast_rcp(1.f + fast_exp2(-fmaf(r0, a[2] + bhn0, xn.x))), -1.f);
    hj0 = fmaf(z0, hj0 - n0, n0);
    float r1 = fast_rcp(1.f + fast_exp2(-(xr.y + a[3])));
    float z1 = fast_rcp(1.f + fast_exp2(-(xz.y + a[4])));
    float n1 = fmaf(2.f, fast_rcp(1.f + fast_exp2(-fmaf(r1, a[5] + bhn1, xn.y))), -1.f);
    hj1 = fmaf(z1, hj1 - n1, n1);

    h2 pv = h2{(_Float16)hj0, (_Float16)hj1};
    if (kc == 0) {
      hbufd[(t & 1) ^ 1][wadr] = __builtin_bit_cast(uint, pv);
      if (hs_out) *(float2*)&hs_out[(size_t)t * HN + u0] = make_float2(hj0, hj1);
    }
    xr = xr_n; xz = xz_n; xn = xn_n;

    // Raw barrier: order the LDS h-write only. Global stores/loads are
    // intentionally NOT drained (fire-and-forget; register-tracked).
    __builtin_amdgcn_sched_barrier(0);
    asm volatile("s_waitcnt lgkmcnt(0)" ::: "memory");
    __builtin_amdgcn_s_barrier();
    __builtin_amdgcn_sched_barrier(0);
  }
  if (hT_out && kc == 0) *(float2*)&hT_out[u0] = make_float2(hj0, hj1);
}

extern "C" void kernel_launch(void* const* d_in, const int* in_sizes, int n_in,
                              void* d_out, int out_size, void* d_ws, size_t ws_size,
                              hipStream_t stream) {
  const float* x     = (const float*)d_in[0];   // [1, 2048, 1739]
  const float* Wih_e = (const float*)d_in[2];   // [768, 1739]
  const float* Whh_e = (const float*)d_in[3];   // [768, 256]
  const float* bih_e = (const float*)d_in[4];   // [768]
  const float* bhh_e = (const float*)d_in[5];   // [768]
  const float* Wih_d = (const float*)d_in[6];
  const float* Whh_d = (const float*)d_in[7];
  const float* bih_d = (const float*)d_in[8];
  const float* bhh_d = (const float*)d_in[9];
  const float* Wout  = (const float*)d_in[10];  // [1739, 256]
  const float* bout  = (const float*)d_in[11];  // [1739]
  float* out = (float*)d_out;                   // [2048, 1, 1739]

  float* ws = (float*)d_ws;
  float* xpe  = ws;                              // 2048*768
  float* xpd  = xpe + (size_t)TT * H3;           // 2048*768  (xpe over-read pad)
  float* hs   = xpd + (size_t)TT * H3;           // 2048*256  (xpd over-read pad)
  float* henc = hs + (size_t)TT * HN;            // 256

  dim3 blk(256);
  // x-projections, pre-scaled for exp2-based gates:
  //   rows [0,512) (r,z): (x@W^T + bih + bhh) * log2e
  //   rows [512,768) (n): (x@W^T + bih) * 2log2e   (bhh n-part in-gate)
  gemm_abt<<<dim3(12, 32), blk, 0, stream>>>(x, TT, II, Wih_e, H3, bih_e, bhh_e, 2 * HN,
                                             L2E, 2.f * L2E, 2 * HN, xpe);
  gemm_abt<<<dim3(12, 32), blk, 0, stream>>>(x, TT, II, Wih_d, H3, bih_d, bhh_d, 2 * HN,
                                             L2E, 2.f * L2E, 2 * HN, xpd);
  // encoder scan -> henc
  gru_seq<<<1, 512, 0, stream>>>(xpe, Whh_e, bhh_e, nullptr, nullptr, henc);
  // decoder scan -> hs
  gru_seq<<<1, 512, 0, stream>>>(xpd, Whh_d, bhh_d, henc, hs, nullptr);
  // output projection (unscaled)
  gemm_abt<<<dim3(28, 32), blk, 0, stream>>>(hs, TT, HN, Wout, II, bout, nullptr, 0,
                                             1.f, 1.f, 0, out);
}